// Round 7
// baseline (109.580 us; speedup 1.0000x reference)
//
#include <hip/hip_runtime.h>
#include <math.h>

#define N_TOK 2048
#define NDIM 512
#define HEADS 8
#define TOPK 16
#define QCOLS 4096   // similarity columns
#define MCOLS 4352   // 4096 sim cols + 256 D cols (x . down256 appended)

typedef __attribute__((ext_vector_type(8))) _Float16 f16x8;
typedef __attribute__((ext_vector_type(4))) float f32x4;

__device__ __forceinline__ unsigned short f32_to_f16(float f) {
    _Float16 h = (_Float16)f;
    return __builtin_bit_cast(unsigned short, h);
}
__device__ __forceinline__ float f16_to_f32(unsigned short u) {
    return (float)__builtin_bit_cast(_Float16, u);
}
__device__ __forceinline__ void gl_lds16(const void* g, void* l) {
    __builtin_amdgcn_global_load_lds(
        (const __attribute__((address_space(1))) void*)g,
        (__attribute__((address_space(3))) void*)l, 16, 0, 0);
}

// ---------------- kPrep: (a) split x -> xh+xl fp16; (b) down rows -> Mt rows 4096.. as fp16 hi/lo
__global__ __launch_bounds__(256) void kPrep(const float* __restrict__ x,
                                             const float* __restrict__ down,
                                             unsigned short* __restrict__ xh,
                                             unsigned short* __restrict__ xl,
                                             unsigned short* __restrict__ Mth,
                                             unsigned short* __restrict__ Mtl) {
    const int bid = blockIdx.x;
    const int tid = threadIdx.x;
    if (bid < 1024) {               // x split: one float4 per thread
        const int i = bid * 256 + tid;
        float4 v = reinterpret_cast<const float4*>(x)[i];
        float vv[4] = {v.x, v.y, v.z, v.w};
        ushort4 h, lo;
        unsigned short* hp = &h.x; unsigned short* lp = &lo.x;
        #pragma unroll
        for (int t = 0; t < 4; ++t) {
            unsigned short hh = f32_to_f16(vv[t]);
            hp[t] = hh;
            lp[t] = f32_to_f16(vv[t] - f16_to_f32(hh));
        }
        reinterpret_cast<ushort4*>(xh)[i] = h;
        reinterpret_cast<ushort4*>(xl)[i] = lo;
    } else {                        // down row e -> Mt row 4096+e (fp16 hi/lo)
        const int e = bid - 1024;   // 0..255
        const int d0 = tid * 2;
        float2 v = *reinterpret_cast<const float2*>(&down[(size_t)e * NDIM + d0]);
        ushort2 h, lo;
        unsigned short h0 = f32_to_f16(v.x);
        unsigned short h1 = f32_to_f16(v.y);
        h.x = h0; h.y = h1;
        lo.x = f32_to_f16(v.x - f16_to_f32(h0));
        lo.y = f32_to_f16(v.y - f16_to_f32(h1));
        *reinterpret_cast<ushort2*>(&Mth[(size_t)(QCOLS + e) * NDIM + d0]) = h;
        *reinterpret_cast<ushort2*>(&Mtl[(size_t)(QCOLS + e) * NDIM + d0]) = lo;
    }
}

// ---------------- K1: M[c, col] = sum_d Wq[c, off+d] * keys[h,k,p,d]  (fp32 VALU),
// written TRANSPOSED as fp16 hi/lo: Mth/Mtl[col][c]. Register-prefetch pipelined.
__global__ __launch_bounds__(256) void k1_combine(const float* __restrict__ Wq,
                                                  const float* __restrict__ keys,
                                                  unsigned short* __restrict__ Mth,
                                                  unsigned short* __restrict__ Mtl) {
    __shared__ float As[16][64];
    __shared__ float Bs[16][64];
    const int ph = blockIdx.z;       // p*8 + h
    const int p = ph >> 3, h = ph & 7;
    const int off = p * 2048 + h * 256;
    const int c0 = blockIdx.x * 64;
    const int k0 = blockIdx.y * 64;
    const int tid = threadIdx.x;
    const int lr = tid >> 2;
    const int ld4 = (tid & 3) * 4;
    const int tr = tid >> 4, tc = tid & 15;
    float acc[4][4] = {};
    const float* ap = &Wq[(size_t)(c0 + lr) * QCOLS + off + ld4];
    const float* bp = &keys[(size_t)((h * 256 + (k0 + lr)) * 2 + p) * 256 + ld4];
    float4 av = *reinterpret_cast<const float4*>(ap);
    float4 bv = *reinterpret_cast<const float4*>(bp);
    for (int d0 = 0; d0 < 256; d0 += 16) {
        __syncthreads();
        As[ld4 + 0][lr] = av.x; As[ld4 + 1][lr] = av.y; As[ld4 + 2][lr] = av.z; As[ld4 + 3][lr] = av.w;
        Bs[ld4 + 0][lr] = bv.x; Bs[ld4 + 1][lr] = bv.y; Bs[ld4 + 2][lr] = bv.z; Bs[ld4 + 3][lr] = bv.w;
        __syncthreads();
        if (d0 + 16 < 256) {
            av = *reinterpret_cast<const float4*>(ap + d0 + 16);
            bv = *reinterpret_cast<const float4*>(bp + d0 + 16);
        }
        #pragma unroll
        for (int kk = 0; kk < 16; ++kk) {
            float4 a = *reinterpret_cast<const float4*>(&As[kk][tr * 4]);
            float4 b = *reinterpret_cast<const float4*>(&Bs[kk][tc * 4]);
            float aa[4] = {a.x, a.y, a.z, a.w}, bb[4] = {b.x, b.y, b.z, b.w};
            #pragma unroll
            for (int i = 0; i < 4; ++i)
                #pragma unroll
                for (int j = 0; j < 4; ++j) acc[i][j] += aa[i] * bb[j];
        }
    }
    #pragma unroll
    for (int j = 0; j < 4; ++j) {
        const int col = off + k0 + tc * 4 + j;
        ushort4 h4, l4;
        unsigned short* hp = &h4.x; unsigned short* lp = &l4.x;
        #pragma unroll
        for (int i = 0; i < 4; ++i) {
            float v = acc[i][j];
            unsigned short hh = f32_to_f16(v);
            hp[i] = hh;
            lp[i] = f32_to_f16(v - f16_to_f32(hh));
        }
        *reinterpret_cast<ushort4*>(&Mth[(size_t)col * NDIM + c0 + tr * 4]) = h4;
        *reinterpret_cast<ushort4*>(&Mtl[(size_t)col * NDIM + c0 + tr * 4]) = l4;
    }
}

// ---------------- K2: sim = xh*Mh + xh*Ml + xl*Mh, fp16 3-term split.
// T3/T4: 3-buffer LDS, 2-deep prefetch, raw s_barrier + counted vmcnt(6) —
// stage(s+2)'s loads stay in flight ACROSS the barrier; only stage(s+1) drains.
// T5: setprio(1) around the MFMA cluster. Numerics bit-identical to R6.
#define BM 64
#define BN 128
#define BK 32
#define ABYTES 8192      // 64 rows * 128B
#define BUFBYTES 24576
#define NSTEP 16
__global__ __launch_bounds__(256, 2) void k2_mfma(const unsigned short* __restrict__ xh,
                                                  const unsigned short* __restrict__ xl,
                                                  const unsigned short* __restrict__ Mth,
                                                  const unsigned short* __restrict__ Mtl,
                                                  float* __restrict__ C) {
    __shared__ __align__(16) char lds[3 * BUFBYTES];   // 72 KB
    const int tid = threadIdx.x;
    const int w = tid >> 6, l = tid & 63;
    const int row0 = blockIdx.x * BM;
    const int col0 = blockIdx.y * BN;
    const int wm = w >> 1, wn = w & 1;     // wave tile: 32 x 64
    f32x4 acc[2][4] = {};

    // staging: linear LDS dest (wave-uniform base + lane*16), inverse-swizzled source
    auto stage = [&](int buf, int s) {
        const int kk = s * BK;
        char* base = lds + buf * BUFBYTES;
        #pragma unroll
        for (int t = 0; t < 2; ++t) {                 // A tile: 8 KB
            const int q = w * 2048 + t * 1024 + l * 16;
            const int r = q >> 7;
            const int bsw = (q & 127) ^ ((r & 7) << 4);
            const unsigned short* src = (bsw < 64)
                ? xh + (size_t)(row0 + r) * NDIM + kk + (bsw >> 1)
                : xl + (size_t)(row0 + r) * NDIM + kk + ((bsw - 64) >> 1);
            gl_lds16(src, base + w * 2048 + t * 1024);
        }
        #pragma unroll
        for (int t = 0; t < 4; ++t) {                 // B tile: 16 KB
            const int q = w * 4096 + t * 1024 + l * 16;
            const int r = q >> 7;
            const int bsw = (q & 127) ^ ((r & 7) << 4);
            const unsigned short* src = (bsw < 64)
                ? Mth + (size_t)(col0 + r) * NDIM + kk + (bsw >> 1)
                : Mtl + (size_t)(col0 + r) * NDIM + kk + ((bsw - 64) >> 1);
            gl_lds16(src, base + ABYTES + w * 4096 + t * 1024);
        }
    };

    stage(0, 0);
    stage(1, 1);
    asm volatile("s_waitcnt vmcnt(6)" ::: "memory");   // buf0 done; buf1 in flight
    __builtin_amdgcn_s_barrier();
    for (int s = 0; s < NSTEP; ++s) {
        if (s + 2 < NSTEP) stage((s + 2) % 3, s + 2);
        const char* base = lds + (s % 3) * BUFBYTES;
        const int bq = (l >> 4) * 16;                  // lane's 16B k-slot
        f16x8 ah[2], al[2], bh[4], bl[4];
        #pragma unroll
        for (int mi = 0; mi < 2; ++mi) {
            const int ra = wm * 32 + mi * 16 + (l & 15);
            const int swz = (ra & 7) << 4;
            ah[mi] = *(const f16x8*)(base + ra * 128 + (bq ^ swz));
            al[mi] = *(const f16x8*)(base + ra * 128 + ((bq + 64) ^ swz));
        }
        #pragma unroll
        for (int nj = 0; nj < 4; ++nj) {
            const int rb = wn * 64 + nj * 16 + (l & 15);
            const int swz = (rb & 7) << 4;
            bh[nj] = *(const f16x8*)(base + ABYTES + rb * 128 + (bq ^ swz));
            bl[nj] = *(const f16x8*)(base + ABYTES + rb * 128 + ((bq + 64) ^ swz));
        }
        __builtin_amdgcn_s_setprio(1);
        #pragma unroll
        for (int mi = 0; mi < 2; ++mi)
            #pragma unroll
            for (int nj = 0; nj < 4; ++nj) {
                acc[mi][nj] = __builtin_amdgcn_mfma_f32_16x16x32_f16(ah[mi], bh[nj], acc[mi][nj], 0, 0, 0);
                acc[mi][nj] = __builtin_amdgcn_mfma_f32_16x16x32_f16(ah[mi], bl[nj], acc[mi][nj], 0, 0, 0);
                acc[mi][nj] = __builtin_amdgcn_mfma_f32_16x16x32_f16(al[mi], bh[nj], acc[mi][nj], 0, 0, 0);
            }
        __builtin_amdgcn_s_setprio(0);
        // drain ONLY stage(s+1); stage(s+2)'s 6 loads stay in flight across barrier
        if (s + 2 < NSTEP) asm volatile("s_waitcnt vmcnt(6)" ::: "memory");
        else               asm volatile("s_waitcnt vmcnt(0)" ::: "memory");
        __builtin_amdgcn_sched_barrier(0);
        __builtin_amdgcn_s_barrier();
    }
    #pragma unroll
    for (int mi = 0; mi < 2; ++mi)
        #pragma unroll
        for (int nj = 0; nj < 4; ++nj)
            #pragma unroll
            for (int r = 0; r < 4; ++r) {
                const int row = row0 + wm * 32 + mi * 16 + (l >> 4) * 4 + r;
                const int col = col0 + wn * 64 + nj * 16 + (l & 15);
                C[(size_t)row * MCOLS + col] = acc[mi][nj][r];
            }
}

// ---------------- K3: selection via sorting networks; outputs dense W[2048,256]
__device__ const unsigned short CAND_TBL[32] = {
    0x0100, 0x0302, 0x0504, 0x0706, 0x0908, 0x0B0A, 0x0D0C, 0x0F0E,
    0x1110, 0x1312, 0x1514, 0x1716,
    0x2120, 0x2322, 0x3024, 0x3231, 0x4033, 0x4241,
    0x5150, 0x6160, 0x7170,
    0x9080, 0xB0A0, 0xD0C0, 0xF0E0,
    0xFFFF, 0xFFFF, 0xFFFF, 0xFFFF, 0xFFFF, 0xFFFF, 0xFFFF
};

__device__ __forceinline__ float sel16(const float a[16], int i) {
    float b0 = (i & 1) ? a[1] : a[0];
    float b1 = (i & 1) ? a[3] : a[2];
    float b2 = (i & 1) ? a[5] : a[4];
    float b3 = (i & 1) ? a[7] : a[6];
    float b4 = (i & 1) ? a[9] : a[8];
    float b5 = (i & 1) ? a[11] : a[10];
    float b6 = (i & 1) ? a[13] : a[12];
    float b7 = (i & 1) ? a[15] : a[14];
    float c0 = (i & 2) ? b1 : b0;
    float c1 = (i & 2) ? b3 : b2;
    float c2 = (i & 2) ? b5 : b4;
    float c3 = (i & 2) ? b7 : b6;
    float d0 = (i & 4) ? c1 : c0;
    float d1 = (i & 4) ? c3 : c2;
    return (i & 8) ? d1 : d0;
}

__global__ __launch_bounds__(256) void k3_sel(const float* __restrict__ sim,
                                              float* __restrict__ W) {
    __shared__ unsigned long long ckey[8][50];
    __shared__ float winval[8][16];
    __shared__ int winflat[8][16];
    __shared__ int Wrow[256];

    const int tid = threadIdx.x;
    const int n = blockIdx.x;
    const int h = tid >> 5;
    const int lam = tid & 15;
    const int p = (tid >> 4) & 1;

    Wrow[tid] = 0;

    const float* s = sim + (size_t)n * MCOLS + p * 2048 + h * 256 + lam * 16;
    float v[16];
    #pragma unroll
    for (int c = 0; c < 4; ++c) {
        float4 t = *reinterpret_cast<const float4*>(s + c * 4);
        v[c * 4 + 0] = t.x; v[c * 4 + 1] = t.y; v[c * 4 + 2] = t.z; v[c * 4 + 3] = t.w;
    }

    #pragma unroll
    for (int k = 2; k <= 16; k <<= 1)
        #pragma unroll
        for (int j = k >> 1; j > 0; j >>= 1)
            #pragma unroll
            for (int i = 0; i < 16; ++i) {
                const int l2 = i ^ j;
                if (l2 > i) {
                    const bool asc = ((i & k) == 0);
                    const float lo = fminf(v[i], v[l2]), hi = fmaxf(v[i], v[l2]);
                    v[i] = asc ? lo : hi;
                    v[l2] = asc ? hi : lo;
                }
            }

    #pragma unroll
    for (int lvl = 1; lvl <= 8; lvl <<= 1) {
        float m[16];
        #pragma unroll
        for (int q = 0; q < 16; ++q)
            m[q] = fmaxf(v[q], __shfl_xor(v[15 - q], lvl));
        #pragma unroll
        for (int j = 8; j > 0; j >>= 1)
            #pragma unroll
            for (int i = 0; i < 16; ++i) {
                const int l2 = i ^ j;
                if (l2 > i) {
                    const float lo = fminf(m[i], m[l2]), hi = fmaxf(m[i], m[l2]);
                    m[i] = lo; m[l2] = hi;
                }
            }
        #pragma unroll
        for (int q = 0; q < 16; ++q) v[q] = m[q];
    }

    float other[16];
    #pragma unroll
    for (int q = 0; q < 16; ++q) other[q] = __shfl_xor(v[q], 16);
    const bool isP1 = (tid & 16) != 0;
    float sxd[16], syd[16];
    #pragma unroll
    for (int q = 0; q < 16; ++q) {
        const float own = v[15 - q], oth = other[15 - q];
        sxd[q] = isP1 ? oth : own;
        syd[q] = isP1 ? own : oth;
    }

    const int lc = tid & 31;
    const unsigned int cw = CAND_TBL[lc];
    unsigned long long mykey[2]; float myval[2]; int myflat[2]; int myrank[2] = {0, 0};
    #pragma unroll
    for (int u = 0; u < 2; ++u) {
        const int fl = (cw >> (8 * u)) & 0xFF;
        const float sv = sel16(sxd, fl >> 4) + sel16(syd, fl & 15);
        const unsigned int uv = __float_as_uint(sv);
        const unsigned int mo = (uv & 0x80000000u) ? ~uv : (uv | 0x80000000u);
        mykey[u] = ((unsigned long long)mo << 8) | (unsigned long long)(255 - fl);
        myval[u] = sv; myflat[u] = fl;
        const int slot = lc * 2 + u;
        if (slot < 50) ckey[h][slot] = mykey[u];
    }
    __syncthreads();
    for (int kk = 0; kk < 50; ++kk) {
        const unsigned long long ok = ckey[h][kk];
        myrank[0] += (ok > mykey[0]) ? 1 : 0;
        myrank[1] += (ok > mykey[1]) ? 1 : 0;
    }
    #pragma unroll
    for (int u = 0; u < 2; ++u)
        if (myrank[u] < 16) { winval[h][myrank[u]] = myval[u]; winflat[h][myrank[u]] = myflat[u]; }
    __syncthreads();

    if (!(tid & 16)) {
        const float sc = winval[h][lam];
        const float m0 = winval[h][0];
        float e = expf(sc - m0);
        float esum = e;
        #pragma unroll
        for (int off = 1; off < 16; off <<= 1) esum += __shfl_xor(esum, off);
        const int fl = winflat[h][lam];
        const float hv = sim[(size_t)n * MCOLS + QCOLS + fl];
        const float g = 0.5f * hv * (1.0f + erff(hv * 0.70710678118654752f));
        const float w = (e / esum) * g;
        atomicAdd(&Wrow[fl], __float2int_rn(w * 4194304.0f));
    }
    __syncthreads();
    W[(size_t)n * 256 + tid] = (float)Wrow[tid] * (1.0f / 4194304.0f);
}

// ---------------- K5: out[2048,512] = W[2048,256] @ up[0:256,512]  (fp32 VALU)
// 32x64 tiles -> 512 blocks (2/CU); register-prefetch pipelined.
__global__ __launch_bounds__(256) void k5_out(const float* __restrict__ W,
                                              const float* __restrict__ up,
                                              float* __restrict__ out) {
    __shared__ float As[16][32];
    __shared__ float Bs[16][64];
    const int row0 = blockIdx.x * 32;
    const int col0 = blockIdx.y * 64;
    const int tid = threadIdx.x;
    const int ar = tid & 31, ak = (tid >> 5) * 2;
    const int bk = tid >> 4, bc = (tid & 15) * 4;
    const int r0 = (tid >> 4) * 2, c0 = (tid & 15) * 4;
    float acc[2][4] = {};
    const float* wp = &W[(size_t)(row0 + ar) * 256 + ak];
    const float* up0 = &up[(size_t)bk * NDIM + col0 + bc];
    float2 a2 = *reinterpret_cast<const float2*>(wp);
    float4 b4 = *reinterpret_cast<const float4*>(up0);
    for (int k0 = 0; k0 < 256; k0 += 16) {
        __syncthreads();
        As[ak + 0][ar] = a2.x;
        As[ak + 1][ar] = a2.y;
        *reinterpret_cast<float4*>(&Bs[bk][bc]) = b4;
        __syncthreads();
        if (k0 + 16 < 256) {
            a2 = *reinterpret_cast<const float2*>(wp + k0 + 16);
            b4 = *reinterpret_cast<const float4*>(up0 + (size_t)16 * NDIM + (size_t)k0 * NDIM);
        }
        #pragma unroll
        for (int kk = 0; kk < 16; ++kk) {
            const float a0 = As[kk][r0], a1 = As[kk][r0 + 1];
            float4 b = *reinterpret_cast<const float4*>(&Bs[kk][c0]);
            float bb[4] = {b.x, b.y, b.z, b.w};
            #pragma unroll
            for (int j = 0; j < 4; ++j) {
                acc[0][j] += a0 * bb[j];
                acc[1][j] += a1 * bb[j];
            }
        }
    }
    #pragma unroll
    for (int i = 0; i < 2; ++i) {
        float4 o = {acc[i][0], acc[i][1], acc[i][2], acc[i][3]};
        *reinterpret_cast<float4*>(&out[(size_t)(row0 + r0 + i) * NDIM + col0 + c0]) = o;
    }
}

extern "C" void kernel_launch(void* const* d_in, const int* in_sizes, int n_in,
                              void* d_out, int out_size, void* d_ws, size_t ws_size,
                              hipStream_t stream) {
    const float* x    = (const float*)d_in[0];
    const float* Wq   = (const float*)d_in[1];
    const float* keys = (const float*)d_in[2];
    const float* down = (const float*)d_in[3];
    const float* up   = (const float*)d_in[4];
    float* out = (float*)d_out;

    char* ws = (char*)d_ws;
    unsigned short* Mth = (unsigned short*)(ws);                       // 4352*512*2 = 4,456,448
    unsigned short* Mtl = (unsigned short*)(ws + 4456448);             // 4,456,448
    unsigned short* xh  = (unsigned short*)(ws + 8912896);             // 2,097,152
    unsigned short* xl  = (unsigned short*)(ws + 11010048);            // 2,097,152
    float* sim          = (float*)(ws + 13107200);                     // 35,651,584
    float* W            = (float*)(ws + 48758784);                     // 2,097,152

    kPrep<<<1280, 256, 0, stream>>>(x, down, xh, xl, Mth, Mtl);
    k1_combine<<<dim3(8, 4, 16), 256, 0, stream>>>(Wq, keys, Mth, Mtl);
    k2_mfma<<<dim3(32, 34), 256, 0, stream>>>(xh, xl, Mth, Mtl, sim);
    k3_sel<<<2048, 256, 0, stream>>>(sim, W);
    k5_out<<<dim3(64, 8), 256, 0, stream>>>(W, up, out);
}

// Round 8
// 101.921 us; speedup vs baseline: 1.0751x; 1.0751x over previous
//
#include <hip/hip_runtime.h>
#include <math.h>

#define N_TOK 2048
#define NDIM 512
#define HEADS 8
#define TOPK 16
#define QCOLS 4096

typedef __attribute__((ext_vector_type(8))) _Float16 f16x8;
typedef __attribute__((ext_vector_type(4))) float f32x4;

__device__ __forceinline__ unsigned short f32_to_f16(float f) {
    _Float16 h = (_Float16)f;
    return __builtin_bit_cast(unsigned short, h);
}
__device__ __forceinline__ float f16_to_f32(unsigned short u) {
    return (float)__builtin_bit_cast(_Float16, u);
}
__device__ __forceinline__ void gl_lds16(const void* g, void* l) {
    __builtin_amdgcn_global_load_lds(
        (const __attribute__((address_space(1))) void*)g,
        (__attribute__((address_space(3))) void*)l, 16, 0, 0);
}

// ---------------- K0: fused prep (x-split, down-split) + k1 (Wq@keys -> Mt fp16 hi/lo)
// bid 0..255: x split; 256..511: down rows -> Mt rows 4096..4351; 512..1023: k1.
__global__ __launch_bounds__(256) void k0_prep(const float* __restrict__ x,
                                               const float* __restrict__ down,
                                               const float* __restrict__ Wq,
                                               const float* __restrict__ keys,
                                               unsigned short* __restrict__ xh,
                                               unsigned short* __restrict__ xl,
                                               unsigned short* __restrict__ Mth,
                                               unsigned short* __restrict__ Mtl) {
    const int bid = blockIdx.x;
    const int tid = threadIdx.x;
    if (bid < 256) {                 // x split: 4 float4 per thread
        #pragma unroll
        for (int t = 0; t < 4; ++t) {
            const int i = bid * 1024 + t * 256 + tid;
            float4 v = reinterpret_cast<const float4*>(x)[i];
            float vv[4] = {v.x, v.y, v.z, v.w};
            ushort4 h, lo;
            unsigned short* hp = &h.x; unsigned short* lp = &lo.x;
            #pragma unroll
            for (int q = 0; q < 4; ++q) {
                unsigned short hh = f32_to_f16(vv[q]);
                hp[q] = hh;
                lp[q] = f32_to_f16(vv[q] - f16_to_f32(hh));
            }
            reinterpret_cast<ushort4*>(xh)[i] = h;
            reinterpret_cast<ushort4*>(xl)[i] = lo;
        }
        return;
    }
    if (bid < 512) {                 // down row e -> Mt row 4096+e
        const int e = bid - 256;
        const int d0 = tid * 2;
        float2 v = *reinterpret_cast<const float2*>(&down[(size_t)e * NDIM + d0]);
        ushort2 h, lo;
        unsigned short h0 = f32_to_f16(v.x);
        unsigned short h1 = f32_to_f16(v.y);
        h.x = h0; h.y = h1;
        lo.x = f32_to_f16(v.x - f16_to_f32(h0));
        lo.y = f32_to_f16(v.y - f16_to_f32(h1));
        *reinterpret_cast<ushort2*>(&Mth[(size_t)(QCOLS + e) * NDIM + d0]) = h;
        *reinterpret_cast<ushort2*>(&Mtl[(size_t)(QCOLS + e) * NDIM + d0]) = lo;
        return;
    }
    // ---- k1: M[c,col] = sum_d Wq[c,off+d]*keys[h,k,p,d], transposed fp16 hi/lo out
    __shared__ float As[16][64];
    __shared__ float Bs[16][64];
    const int b = bid - 512;
    const int cx = b & 7, ky = (b >> 3) & 3, ph = b >> 5;
    const int p = ph >> 3, h = ph & 7;
    const int off = p * 2048 + h * 256;
    const int c0 = cx * 64;
    const int k0 = ky * 64;
    const int lr = tid >> 2;
    const int ld4 = (tid & 3) * 4;
    const int tr = tid >> 4, tc = tid & 15;
    float acc[4][4] = {};
    const float* ap = &Wq[(size_t)(c0 + lr) * QCOLS + off + ld4];
    const float* bp = &keys[(size_t)((h * 256 + (k0 + lr)) * 2 + p) * 256 + ld4];
    float4 av = *reinterpret_cast<const float4*>(ap);
    float4 bv = *reinterpret_cast<const float4*>(bp);
    for (int d0 = 0; d0 < 256; d0 += 16) {
        __syncthreads();
        As[ld4 + 0][lr] = av.x; As[ld4 + 1][lr] = av.y; As[ld4 + 2][lr] = av.z; As[ld4 + 3][lr] = av.w;
        Bs[ld4 + 0][lr] = bv.x; Bs[ld4 + 1][lr] = bv.y; Bs[ld4 + 2][lr] = bv.z; Bs[ld4 + 3][lr] = bv.w;
        __syncthreads();
        if (d0 + 16 < 256) {
            av = *reinterpret_cast<const float4*>(ap + d0 + 16);
            bv = *reinterpret_cast<const float4*>(bp + d0 + 16);
        }
        #pragma unroll
        for (int kk = 0; kk < 16; ++kk) {
            float4 a = *reinterpret_cast<const float4*>(&As[kk][tr * 4]);
            float4 bq = *reinterpret_cast<const float4*>(&Bs[kk][tc * 4]);
            float aa[4] = {a.x, a.y, a.z, a.w}, bb[4] = {bq.x, bq.y, bq.z, bq.w};
            #pragma unroll
            for (int i = 0; i < 4; ++i)
                #pragma unroll
                for (int j = 0; j < 4; ++j) acc[i][j] += aa[i] * bb[j];
        }
    }
    #pragma unroll
    for (int j = 0; j < 4; ++j) {
        const int col = off + k0 + tc * 4 + j;
        ushort4 h4, l4;
        unsigned short* hp = &h4.x; unsigned short* lp = &l4.x;
        #pragma unroll
        for (int i = 0; i < 4; ++i) {
            float v = acc[i][j];
            unsigned short hh = f32_to_f16(v);
            hp[i] = hh;
            lp[i] = f32_to_f16(v - f16_to_f32(hh));
        }
        *reinterpret_cast<ushort4*>(&Mth[(size_t)col * NDIM + c0 + tr * 4]) = h4;
        *reinterpret_cast<ushort4*>(&Mtl[(size_t)col * NDIM + c0 + tr * 4]) = l4;
    }
}

// ---------------- KF: fused GEMM (xh*Mh+xh*Ml+xl*Mh, fp16 3-term) + phase-1 top-16.
// grid (32 row-tiles, 17 col-groups). BM=64, BN=256, BK=32, double-buffered LDS.
// g<16: (p,h) score group -> epilogue bitonic top-16 per row -> T[n][g][16].
// g==16: D = x.down256 -> D[2048][256] direct store.
#define BM 64
#define BN 256
#define BK 32
#define FBUF 40960    // A 8KB + B 32KB
__global__ __launch_bounds__(256, 2) void kF_gemm(const unsigned short* __restrict__ xh,
                                                  const unsigned short* __restrict__ xl,
                                                  const unsigned short* __restrict__ Mth,
                                                  const unsigned short* __restrict__ Mtl,
                                                  float* __restrict__ T,
                                                  float* __restrict__ D) {
    __shared__ __align__(16) char lds[2 * FBUF];   // 80 KB
    const int tid = threadIdx.x;
    const int w = tid >> 6, l = tid & 63;
    const int row0 = blockIdx.x * BM;
    const int g = blockIdx.y;
    const int colbase = g * 256;
    f32x4 acc[4][4] = {};

    auto stage = [&](int buf, int s) {
        const int kk = s * BK;
        char* base = lds + buf * FBUF;
        #pragma unroll
        for (int t = 0; t < 2; ++t) {                 // A: 8 KB (64 rows x 128B)
            const int q = w * 2048 + t * 1024 + l * 16;
            const int r = q >> 7;
            const int bsw = (q & 127) ^ ((r & 7) << 4);
            const unsigned short* src = (bsw < 64)
                ? xh + (size_t)(row0 + r) * NDIM + kk + (bsw >> 1)
                : xl + (size_t)(row0 + r) * NDIM + kk + ((bsw - 64) >> 1);
            gl_lds16(src, base + w * 2048 + t * 1024);
        }
        #pragma unroll
        for (int t = 0; t < 8; ++t) {                 // B: 32 KB (256 rows x 128B)
            const int q = w * 8192 + t * 1024 + l * 16;
            const int r = q >> 7;
            const int bsw = (q & 127) ^ ((r & 7) << 4);
            const unsigned short* src = (bsw < 64)
                ? Mth + (size_t)(colbase + r) * NDIM + kk + (bsw >> 1)
                : Mtl + (size_t)(colbase + r) * NDIM + kk + ((bsw - 64) >> 1);
            gl_lds16(src, base + 8192 + w * 8192 + t * 1024);
        }
    };

    stage(0, 0);
    __syncthreads();
    for (int s = 0; s < 16; ++s) {
        if (s + 1 < 16) stage((s + 1) & 1, s + 1);
        const char* base = lds + (s & 1) * FBUF;
        const int bq = (l >> 4) * 16;
        f16x8 ah[4], al[4], bh[4], bl[4];
        #pragma unroll
        for (int mi = 0; mi < 4; ++mi) {
            const int ra = mi * 16 + (l & 15);
            const int swz = (ra & 7) << 4;
            ah[mi] = *(const f16x8*)(base + ra * 128 + (bq ^ swz));
            al[mi] = *(const f16x8*)(base + ra * 128 + ((bq + 64) ^ swz));
        }
        #pragma unroll
        for (int nj = 0; nj < 4; ++nj) {
            const int rb = w * 64 + nj * 16 + (l & 15);
            const int swz = (rb & 7) << 4;
            bh[nj] = *(const f16x8*)(base + 8192 + rb * 128 + (bq ^ swz));
            bl[nj] = *(const f16x8*)(base + 8192 + rb * 128 + ((bq + 64) ^ swz));
        }
        __builtin_amdgcn_s_setprio(1);
        #pragma unroll
        for (int mi = 0; mi < 4; ++mi)
            #pragma unroll
            for (int nj = 0; nj < 4; ++nj) {
                acc[mi][nj] = __builtin_amdgcn_mfma_f32_16x16x32_f16(ah[mi], bh[nj], acc[mi][nj], 0, 0, 0);
                acc[mi][nj] = __builtin_amdgcn_mfma_f32_16x16x32_f16(ah[mi], bl[nj], acc[mi][nj], 0, 0, 0);
                acc[mi][nj] = __builtin_amdgcn_mfma_f32_16x16x32_f16(al[mi], bh[nj], acc[mi][nj], 0, 0, 0);
            }
        __builtin_amdgcn_s_setprio(0);
        __syncthreads();
    }

    if (g == 16) {   // D block: direct store
        #pragma unroll
        for (int mi = 0; mi < 4; ++mi)
            #pragma unroll
            for (int nj = 0; nj < 4; ++nj)
                #pragma unroll
                for (int r = 0; r < 4; ++r) {
                    const int row = row0 + mi * 16 + (l >> 4) * 4 + r;
                    const int col = w * 64 + nj * 16 + (l & 15);
                    D[(size_t)row * 256 + col] = acc[mi][nj][r];
                }
        return;
    }

    // ---- epilogue: C -> LDS [64][260], then per-row bitonic top-16 -> T
    float* Cl = (float*)lds;
    #pragma unroll
    for (int mi = 0; mi < 4; ++mi)
        #pragma unroll
        for (int nj = 0; nj < 4; ++nj)
            #pragma unroll
            for (int r = 0; r < 4; ++r)
                Cl[(mi * 16 + (l >> 4) * 4 + r) * 260 + w * 64 + nj * 16 + (l & 15)] = acc[mi][nj][r];
    __syncthreads();

    const int grp = tid >> 4;        // 16 groups, 4 rows each
    const int lam = tid & 15;
    #pragma unroll
    for (int rr = 0; rr < 4; ++rr) {
        const int row = grp * 4 + rr;
        float v[16];
        #pragma unroll
        for (int j = 0; j < 16; ++j) v[j] = Cl[row * 260 + lam + 16 * j];

        // in-lane bitonic sort ascending
        #pragma unroll
        for (int k = 2; k <= 16; k <<= 1)
            #pragma unroll
            for (int j = k >> 1; j > 0; j >>= 1)
                #pragma unroll
                for (int i = 0; i < 16; ++i) {
                    const int l2 = i ^ j;
                    if (l2 > i) {
                        const bool asc = ((i & k) == 0);
                        const float lo = fminf(v[i], v[l2]), hi = fmaxf(v[i], v[l2]);
                        v[i] = asc ? lo : hi;
                        v[l2] = asc ? hi : lo;
                    }
                }
        // 4 cross-lane merge levels
        #pragma unroll
        for (int lvl = 1; lvl <= 8; lvl <<= 1) {
            float m[16];
            #pragma unroll
            for (int q = 0; q < 16; ++q)
                m[q] = fmaxf(v[q], __shfl_xor(v[15 - q], lvl));
            #pragma unroll
            for (int j = 8; j > 0; j >>= 1)
                #pragma unroll
                for (int i = 0; i < 16; ++i) {
                    const int l2 = i ^ j;
                    if (l2 > i) {
                        const float lo = fminf(m[i], m[l2]), hi = fmaxf(m[i], m[l2]);
                        m[i] = lo; m[l2] = hi;
                    }
                }
            #pragma unroll
            for (int q = 0; q < 16; ++q) v[q] = m[q];
        }
        // lane lam writes rank-lam (descending)
        const int n = row0 + row;
        T[((size_t)n * 16 + g) * 16 + lam] = v[15 - lam];
    }
}

// ---------------- KC: combine per token: 50 monotone candidates -> top-16 ->
// softmax * gelu(D) -> dense W[2048][256] (fixed-point scatter)
__device__ const unsigned short CAND_TBL[32] = {
    0x0100, 0x0302, 0x0504, 0x0706, 0x0908, 0x0B0A, 0x0D0C, 0x0F0E,
    0x1110, 0x1312, 0x1514, 0x1716,
    0x2120, 0x2322, 0x3024, 0x3231, 0x4033, 0x4241,
    0x5150, 0x6160, 0x7170,
    0x9080, 0xB0A0, 0xD0C0, 0xF0E0,
    0xFFFF, 0xFFFF, 0xFFFF, 0xFFFF, 0xFFFF, 0xFFFF, 0xFFFF
};

__device__ __forceinline__ float sel16(const float a[16], int i) {
    float b0 = (i & 1) ? a[1] : a[0];
    float b1 = (i & 1) ? a[3] : a[2];
    float b2 = (i & 1) ? a[5] : a[4];
    float b3 = (i & 1) ? a[7] : a[6];
    float b4 = (i & 1) ? a[9] : a[8];
    float b5 = (i & 1) ? a[11] : a[10];
    float b6 = (i & 1) ? a[13] : a[12];
    float b7 = (i & 1) ? a[15] : a[14];
    float c0 = (i & 2) ? b1 : b0;
    float c1 = (i & 2) ? b3 : b2;
    float c2 = (i & 2) ? b5 : b4;
    float c3 = (i & 2) ? b7 : b6;
    float d0 = (i & 4) ? c1 : c0;
    float d1 = (i & 4) ? c3 : c2;
    return (i & 8) ? d1 : d0;
}

__global__ __launch_bounds__(256) void kC_combine(const float* __restrict__ T,
                                                  const float* __restrict__ D,
                                                  float* __restrict__ W) {
    __shared__ unsigned long long ckey[8][50];
    __shared__ float winval[8][16];
    __shared__ int winflat[8][16];
    __shared__ int Wrow[256];

    const int tid = threadIdx.x;
    const int n = blockIdx.x;
    const int h = tid >> 5;
    const int lam = tid & 15;

    Wrow[tid] = 0;

    float sxd[16], syd[16];
    const float* t0 = &T[((size_t)n * 16 + h) * 16];
    const float* t1 = &T[((size_t)n * 16 + 8 + h) * 16];
    #pragma unroll
    for (int q = 0; q < 16; ++q) { sxd[q] = t0[q]; syd[q] = t1[q]; }

    const int lc = tid & 31;
    const unsigned int cw = CAND_TBL[lc];
    unsigned long long mykey[2]; float myval[2]; int myflat[2]; int myrank[2] = {0, 0};
    #pragma unroll
    for (int u = 0; u < 2; ++u) {
        const int fl = (cw >> (8 * u)) & 0xFF;
        const float sv = sel16(sxd, fl >> 4) + sel16(syd, fl & 15);
        const unsigned int uv = __float_as_uint(sv);
        const unsigned int mo = (uv & 0x80000000u) ? ~uv : (uv | 0x80000000u);
        mykey[u] = ((unsigned long long)mo << 8) | (unsigned long long)(255 - fl);
        myval[u] = sv; myflat[u] = fl;
        const int slot = lc * 2 + u;
        if (slot < 50) ckey[h][slot] = mykey[u];
    }
    __syncthreads();
    for (int kk = 0; kk < 50; ++kk) {
        const unsigned long long ok = ckey[h][kk];
        myrank[0] += (ok > mykey[0]) ? 1 : 0;
        myrank[1] += (ok > mykey[1]) ? 1 : 0;
    }
    #pragma unroll
    for (int u = 0; u < 2; ++u)
        if (myrank[u] < 16) { winval[h][myrank[u]] = myval[u]; winflat[h][myrank[u]] = myflat[u]; }
    __syncthreads();

    if (!(tid & 16)) {
        const float sc = winval[h][lam];
        const float m0 = winval[h][0];
        float e = expf(sc - m0);
        float esum = e;
        #pragma unroll
        for (int off = 1; off < 16; off <<= 1) esum += __shfl_xor(esum, off);
        const int fl = winflat[h][lam];
        const float hv = D[(size_t)n * 256 + fl];
        const float gg = 0.5f * hv * (1.0f + erff(hv * 0.70710678118654752f));
        const float wv = (e / esum) * gg;
        atomicAdd(&Wrow[fl], __float2int_rn(wv * 4194304.0f));
    }
    __syncthreads();
    W[(size_t)n * 256 + tid] = (float)Wrow[tid] * (1.0f / 4194304.0f);
}

// ---------------- K5: out[2048,512] = W[2048,256] @ up[0:256,512]  (fp32 VALU)
__global__ __launch_bounds__(256) void k5_out(const float* __restrict__ W,
                                              const float* __restrict__ up,
                                              float* __restrict__ out) {
    __shared__ float As[16][32];
    __shared__ float Bs[16][64];
    const int row0 = blockIdx.x * 32;
    const int col0 = blockIdx.y * 64;
    const int tid = threadIdx.x;
    const int ar = tid & 31, ak = (tid >> 5) * 2;
    const int bk = tid >> 4, bc = (tid & 15) * 4;
    const int r0 = (tid >> 4) * 2, c0 = (tid & 15) * 4;
    float acc[2][4] = {};
    const float* wp = &W[(size_t)(row0 + ar) * 256 + ak];
    const float* up0 = &up[(size_t)bk * NDIM + col0 + bc];
    float2 a2 = *reinterpret_cast<const float2*>(wp);
    float4 b4 = *reinterpret_cast<const float4*>(up0);
    for (int k0 = 0; k0 < 256; k0 += 16) {
        __syncthreads();
        As[ak + 0][ar] = a2.x;
        As[ak + 1][ar] = a2.y;
        *reinterpret_cast<float4*>(&Bs[bk][bc]) = b4;
        __syncthreads();
        if (k0 + 16 < 256) {
            a2 = *reinterpret_cast<const float2*>(wp + k0 + 16);
            b4 = *reinterpret_cast<const float4*>(up0 + (size_t)16 * NDIM + (size_t)k0 * NDIM);
        }
        #pragma unroll
        for (int kk = 0; kk < 16; ++kk) {
            const float a0 = As[kk][r0], a1 = As[kk][r0 + 1];
            float4 b = *reinterpret_cast<const float4*>(&Bs[kk][c0]);
            float bb[4] = {b.x, b.y, b.z, b.w};
            #pragma unroll
            for (int j = 0; j < 4; ++j) {
                acc[0][j] += a0 * bb[j];
                acc[1][j] += a1 * bb[j];
            }
        }
    }
    #pragma unroll
    for (int i = 0; i < 2; ++i) {
        float4 o = {acc[i][0], acc[i][1], acc[i][2], acc[i][3]};
        *reinterpret_cast<float4*>(&out[(size_t)(row0 + r0 + i) * NDIM + col0 + c0]) = o;
    }
}

extern "C" void kernel_launch(void* const* d_in, const int* in_sizes, int n_in,
                              void* d_out, int out_size, void* d_ws, size_t ws_size,
                              hipStream_t stream) {
    const float* x    = (const float*)d_in[0];
    const float* Wq   = (const float*)d_in[1];
    const float* keys = (const float*)d_in[2];
    const float* down = (const float*)d_in[3];
    const float* up   = (const float*)d_in[4];
    float* out = (float*)d_out;

    char* ws = (char*)d_ws;
    unsigned short* Mth = (unsigned short*)(ws);                 // 4352*512*2 = 4,456,448
    unsigned short* Mtl = (unsigned short*)(ws + 4456448);       // 4,456,448
    unsigned short* xh  = (unsigned short*)(ws + 8912896);       // 2,097,152
    unsigned short* xl  = (unsigned short*)(ws + 11010048);      // 2,097,152
    float* T            = (float*)(ws + 13107200);               // 2048*16*16*4 = 2,097,152
    float* D            = (float*)(ws + 15204352);               // 2048*256*4  = 2,097,152
    float* W            = (float*)(ws + 17301504);               // 2,097,152

    k0_prep<<<1024, 256, 0, stream>>>(x, down, Wq, keys, xh, xl, Mth, Mtl);
    kF_gemm<<<dim3(32, 17), 256, 0, stream>>>(xh, xl, Mth, Mtl, T, D);
    kC_combine<<<2048, 256, 0, stream>>>(T, D, W);
    k5_out<<<dim3(64, 8), 256, 0, stream>>>(W, up, out);
}

// Round 11
// 94.197 us; speedup vs baseline: 1.1633x; 1.0820x over previous
//
#include <hip/hip_runtime.h>
#include <math.h>

#define N_TOK 2048
#define NDIM 512
#define HEADS 8
#define TOPK 16
#define QCOLS 4096

typedef __attribute__((ext_vector_type(8))) _Float16 f16x8;
typedef __attribute__((ext_vector_type(4))) float f32x4;

__device__ __forceinline__ unsigned short f32_to_f16(float f) {
    _Float16 h = (_Float16)f;
    return __builtin_bit_cast(unsigned short, h);
}
__device__ __forceinline__ float f16_to_f32(unsigned short u) {
    return (float)__builtin_bit_cast(_Float16, u);
}
__device__ __forceinline__ void gl_lds16(const void* g, void* l) {
    __builtin_amdgcn_global_load_lds(
        (const __attribute__((address_space(1))) void*)g,
        (__attribute__((address_space(3))) void*)l, 16, 0, 0);
}

// ---------------- kP: all fp32 -> fp16 hi/lo splits (x, Wq, keys, down->Mt rows, upT)
__device__ __forceinline__ void split_f4(const float* __restrict__ src,
                                         unsigned short* __restrict__ dh,
                                         unsigned short* __restrict__ dl,
                                         int i) {
    float4 v = reinterpret_cast<const float4*>(src)[i];
    float vv[4] = {v.x, v.y, v.z, v.w};
    ushort4 h, lo;
    unsigned short* hp = &h.x; unsigned short* lp = &lo.x;
    #pragma unroll
    for (int q = 0; q < 4; ++q) {
        unsigned short hh = f32_to_f16(vv[q]);
        hp[q] = hh;
        lp[q] = f32_to_f16(vv[q] - f16_to_f32(hh));
    }
    reinterpret_cast<ushort4*>(dh)[i] = h;
    reinterpret_cast<ushort4*>(dl)[i] = lo;
}

__global__ __launch_bounds__(256) void kP_split(const float* __restrict__ x,
                                                const float* __restrict__ Wq,
                                                const float* __restrict__ keys,
                                                const float* __restrict__ down,
                                                const float* __restrict__ up,
                                                unsigned short* __restrict__ xh,
                                                unsigned short* __restrict__ xl,
                                                unsigned short* __restrict__ Wqh,
                                                unsigned short* __restrict__ Wql,
                                                unsigned short* __restrict__ ksh,
                                                unsigned short* __restrict__ ksl,
                                                unsigned short* __restrict__ Mth,
                                                unsigned short* __restrict__ Mtl,
                                                unsigned short* __restrict__ upTh,
                                                unsigned short* __restrict__ upTl) {
    const int bid = blockIdx.x;
    const int tid = threadIdx.x;
    if (bid < 256) {                     // x: 262,144 f4 -> 256 blocks
        #pragma unroll
        for (int t = 0; t < 4; ++t) split_f4(x, xh, xl, bid * 1024 + t * 256 + tid);
        return;
    }
    if (bid < 768) {                     // Wq: 524,288 f4 -> 512 blocks
        const int b = bid - 256;
        #pragma unroll
        for (int t = 0; t < 4; ++t) split_f4(Wq, Wqh, Wql, b * 1024 + t * 256 + tid);
        return;
    }
    if (bid < 1024) {                    // keys: 262,144 f4 -> 256 blocks
        const int b = bid - 768;
        #pragma unroll
        for (int t = 0; t < 4; ++t) split_f4(keys, ksh, ksl, b * 1024 + t * 256 + tid);
        return;
    }
    if (bid < 1280) {                    // down row e -> Mt row 4096+e
        const int e = bid - 1024;
        const int d0 = tid * 2;
        float2 v = *reinterpret_cast<const float2*>(&down[(size_t)e * NDIM + d0]);
        ushort2 h, lo;
        unsigned short h0 = f32_to_f16(v.x);
        unsigned short h1 = f32_to_f16(v.y);
        h.x = h0; h.y = h1;
        lo.x = f32_to_f16(v.x - f16_to_f32(h0));
        lo.y = f32_to_f16(v.y - f16_to_f32(h1));
        *reinterpret_cast<ushort2*>(&Mth[(size_t)(QCOLS + e) * NDIM + d0]) = h;
        *reinterpret_cast<ushort2*>(&Mtl[(size_t)(QCOLS + e) * NDIM + d0]) = lo;
        return;
    }
    // upT: up[e][d] -> upTh/upTl[d][e]   (64 blocks)
    const int b = bid - 1280;            // 0..63
    #pragma unroll
    for (int dd = 0; dd < 8; ++dd) {
        const int d = b * 8 + dd;
        const int e = tid;
        const float v = up[(size_t)e * NDIM + d];
        unsigned short hh = f32_to_f16(v);
        upTh[(size_t)d * 256 + e] = hh;
        upTl[(size_t)d * 256 + e] = f32_to_f16(v - f16_to_f32(hh));
    }
}

// ---------------- kQ: M_block = Wq_slice @ keys^T via fp16 3-term MFMA,
// output transposed fp16 hi/lo into Mth/Mtl[col][c]. grid (16 c-tiles, 16 ph).
__global__ __launch_bounds__(256) void kQ_m1(const unsigned short* __restrict__ Wqh,
                                             const unsigned short* __restrict__ Wql,
                                             const unsigned short* __restrict__ ksh,
                                             const unsigned short* __restrict__ ksl,
                                             unsigned short* __restrict__ Mth,
                                             unsigned short* __restrict__ Mtl) {
    __shared__ __align__(16) char lds[36864];   // A 4KB + B 32KB
    const int tid = threadIdx.x;
    const int w = tid >> 6, l = tid & 63;
    const int c0 = blockIdx.x * 32;
    const int ph = blockIdx.y;
    const int p = ph >> 3, h = ph & 7;
    const int off = p * 2048 + h * 256;
    f32x4 acc[2][4] = {};

    for (int s = 0; s < 8; ++s) {
        const int kk = s * 32;
        __syncthreads();
        {   // A: 32 rows x 128B = 4KB
            const int q = w * 1024 + l * 16;
            const int r = q >> 7;
            const int bsw = (q & 127) ^ ((r & 7) << 4);
            const unsigned short* src = (bsw < 64)
                ? Wqh + (size_t)(c0 + r) * QCOLS + off + kk + (bsw >> 1)
                : Wql + (size_t)(c0 + r) * QCOLS + off + kk + ((bsw - 64) >> 1);
            gl_lds16(src, lds + w * 1024);
        }
        #pragma unroll
        for (int t = 0; t < 8; ++t) {   // B: 256 rows x 128B = 32KB
            const int q = w * 8192 + t * 1024 + l * 16;
            const int r = q >> 7;
            const int bsw = (q & 127) ^ ((r & 7) << 4);
            const unsigned short* src = (bsw < 64)
                ? ksh + ((size_t)(h * 256 + r) * 2 + p) * 256 + kk + (bsw >> 1)
                : ksl + ((size_t)(h * 256 + r) * 2 + p) * 256 + kk + ((bsw - 64) >> 1);
            gl_lds16(src, lds + 4096 + w * 8192 + t * 1024);
        }
        __syncthreads();
        const int bq = (l >> 4) * 16;
        f16x8 ah[2], al[2];
        #pragma unroll
        for (int mi = 0; mi < 2; ++mi) {
            const int ra = mi * 16 + (l & 15);
            const int swz = (ra & 7) << 4;
            ah[mi] = *(const f16x8*)(lds + ra * 128 + (bq ^ swz));
            al[mi] = *(const f16x8*)(lds + ra * 128 + ((bq + 64) ^ swz));
        }
        __builtin_amdgcn_s_setprio(1);
        #pragma unroll
        for (int nj = 0; nj < 4; ++nj) {
            const int rb = w * 64 + nj * 16 + (l & 15);
            const int swz = (rb & 7) << 4;
            f16x8 bh = *(const f16x8*)(lds + 4096 + rb * 128 + (bq ^ swz));
            f16x8 bl = *(const f16x8*)(lds + 4096 + rb * 128 + ((bq + 64) ^ swz));
            #pragma unroll
            for (int mi = 0; mi < 2; ++mi) {
                acc[mi][nj] = __builtin_amdgcn_mfma_f32_16x16x32_f16(ah[mi], bh, acc[mi][nj], 0, 0, 0);
                acc[mi][nj] = __builtin_amdgcn_mfma_f32_16x16x32_f16(ah[mi], bl, acc[mi][nj], 0, 0, 0);
                acc[mi][nj] = __builtin_amdgcn_mfma_f32_16x16x32_f16(al[mi], bh, acc[mi][nj], 0, 0, 0);
            }
        }
        __builtin_amdgcn_s_setprio(0);
    }
    #pragma unroll
    for (int mi = 0; mi < 2; ++mi)
        #pragma unroll
        for (int nj = 0; nj < 4; ++nj) {
            const int k = w * 64 + nj * 16 + (l & 15);
            const int cb = c0 + mi * 16 + (l >> 4) * 4;
            ushort4 h4, l4;
            unsigned short* hp = &h4.x; unsigned short* lp = &l4.x;
            #pragma unroll
            for (int r = 0; r < 4; ++r) {
                const float v = acc[mi][nj][r];
                unsigned short hh = f32_to_f16(v);
                hp[r] = hh;
                lp[r] = f32_to_f16(v - f16_to_f32(hh));
            }
            *reinterpret_cast<ushort4*>(&Mth[(size_t)(off + k) * NDIM + cb]) = h4;
            *reinterpret_cast<ushort4*>(&Mtl[(size_t)(off + k) * NDIM + cb]) = l4;
        }
}

// ---------------- KF: fused sim GEMM + phase-1 top-16. Single 40KB buffer,
// 2-barrier m97 structure, grid (32, 17) = 544 blocks ALL resident (3/CU cap).
#define BM 64
#define BN 256
#define BK 32
__global__ __launch_bounds__(256, 3) void kF_gemm(const unsigned short* __restrict__ xh,
                                                  const unsigned short* __restrict__ xl,
                                                  const unsigned short* __restrict__ Mth,
                                                  const unsigned short* __restrict__ Mtl,
                                                  float* __restrict__ T,
                                                  float* __restrict__ D) {
    __shared__ __align__(16) char lds[40960];   // A 8KB + B 32KB
    const int tid = threadIdx.x;
    const int w = tid >> 6, l = tid & 63;
    const int row0 = blockIdx.x * BM;
    const int g = blockIdx.y;
    const int colbase = g * 256;
    f32x4 acc[4][4] = {};

    for (int s = 0; s < 16; ++s) {
        const int kk = s * BK;
        __syncthreads();
        #pragma unroll
        for (int t = 0; t < 2; ++t) {                 // A: 64 rows x 128B = 8KB
            const int q = w * 2048 + t * 1024 + l * 16;
            const int r = q >> 7;
            const int bsw = (q & 127) ^ ((r & 7) << 4);
            const unsigned short* src = (bsw < 64)
                ? xh + (size_t)(row0 + r) * NDIM + kk + (bsw >> 1)
                : xl + (size_t)(row0 + r) * NDIM + kk + ((bsw - 64) >> 1);
            gl_lds16(src, lds + w * 2048 + t * 1024);
        }
        #pragma unroll
        for (int t = 0; t < 8; ++t) {                 // B: 256 rows x 128B = 32KB
            const int q = w * 8192 + t * 1024 + l * 16;
            const int r = q >> 7;
            const int bsw = (q & 127) ^ ((r & 7) << 4);
            const unsigned short* src = (bsw < 64)
                ? Mth + (size_t)(colbase + r) * NDIM + kk + (bsw >> 1)
                : Mtl + (size_t)(colbase + r) * NDIM + kk + ((bsw - 64) >> 1);
            gl_lds16(src, lds + 8192 + w * 8192 + t * 1024);
        }
        __syncthreads();
        const int bq = (l >> 4) * 16;
        f16x8 ah[4], al[4];
        #pragma unroll
        for (int mi = 0; mi < 4; ++mi) {
            const int ra = mi * 16 + (l & 15);
            const int swz = (ra & 7) << 4;
            ah[mi] = *(const f16x8*)(lds + ra * 128 + (bq ^ swz));
            al[mi] = *(const f16x8*)(lds + ra * 128 + ((bq + 64) ^ swz));
        }
        __builtin_amdgcn_s_setprio(1);
        #pragma unroll
        for (int nj = 0; nj < 4; ++nj) {
            const int rb = w * 64 + nj * 16 + (l & 15);
            const int swz = (rb & 7) << 4;
            f16x8 bh = *(const f16x8*)(lds + 8192 + rb * 128 + (bq ^ swz));
            f16x8 bl = *(const f16x8*)(lds + 8192 + rb * 128 + ((bq + 64) ^ swz));
            #pragma unroll
            for (int mi = 0; mi < 4; ++mi) {
                acc[mi][nj] = __builtin_amdgcn_mfma_f32_16x16x32_f16(ah[mi], bh, acc[mi][nj], 0, 0, 0);
                acc[mi][nj] = __builtin_amdgcn_mfma_f32_16x16x32_f16(ah[mi], bl, acc[mi][nj], 0, 0, 0);
                acc[mi][nj] = __builtin_amdgcn_mfma_f32_16x16x32_f16(al[mi], bh, acc[mi][nj], 0, 0, 0);
            }
        }
        __builtin_amdgcn_s_setprio(0);
    }
    __syncthreads();   // staging reads done before LDS reuse

    if (g == 16) {     // D block: direct store
        #pragma unroll
        for (int mi = 0; mi < 4; ++mi)
            #pragma unroll
            for (int nj = 0; nj < 4; ++nj)
                #pragma unroll
                for (int r = 0; r < 4; ++r) {
                    const int row = row0 + mi * 16 + (l >> 4) * 4 + r;
                    const int col = w * 64 + nj * 16 + (l & 15);
                    D[(size_t)row * 256 + col] = acc[mi][nj][r];
                }
        return;
    }

    // epilogue: 4 chunks of 16 rows; Cl[16][260] = 16.6KB fits the 40KB buffer
    float* Cl = (float*)lds;
    const int grp = tid >> 4;
    const int lam = tid & 15;
    for (int c = 0; c < 4; ++c) {
        #pragma unroll
        for (int nj = 0; nj < 4; ++nj)
            #pragma unroll
            for (int r = 0; r < 4; ++r)
                Cl[((l >> 4) * 4 + r) * 260 + w * 64 + nj * 16 + (l & 15)] = acc[c][nj][r];
        __syncthreads();
        float v[16];
        #pragma unroll
        for (int j = 0; j < 16; ++j) v[j] = Cl[grp * 260 + lam + 16 * j];
        // in-lane bitonic sort ascending
        #pragma unroll
        for (int k = 2; k <= 16; k <<= 1)
            #pragma unroll
            for (int j = k >> 1; j > 0; j >>= 1)
                #pragma unroll
                for (int i = 0; i < 16; ++i) {
                    const int l2 = i ^ j;
                    if (l2 > i) {
                        const bool asc = ((i & k) == 0);
                        const float lo = fminf(v[i], v[l2]), hi = fmaxf(v[i], v[l2]);
                        v[i] = asc ? lo : hi;
                        v[l2] = asc ? hi : lo;
                    }
                }
        // 4 cross-lane merge levels (within 16-lane group)
        #pragma unroll
        for (int lvl = 1; lvl <= 8; lvl <<= 1) {
            float m[16];
            #pragma unroll
            for (int q = 0; q < 16; ++q)
                m[q] = fmaxf(v[q], __shfl_xor(v[15 - q], lvl));
            #pragma unroll
            for (int j = 8; j > 0; j >>= 1)
                #pragma unroll
                for (int i = 0; i < 16; ++i) {
                    const int l2 = i ^ j;
                    if (l2 > i) {
                        const float lo = fminf(m[i], m[l2]), hi = fmaxf(m[i], m[l2]);
                        m[i] = lo; m[l2] = hi;
                    }
                }
            #pragma unroll
            for (int q = 0; q < 16; ++q) v[q] = m[q];
        }
        const int n = row0 + c * 16 + grp;
        T[((size_t)n * 16 + g) * 16 + lam] = v[15 - lam];
        __syncthreads();
    }
}

// ---------------- KC: 50 monotone candidates -> top-16 -> softmax*gelu(D) ->
// dense W as fp16 hi/lo
__device__ const unsigned short CAND_TBL[32] = {
    0x0100, 0x0302, 0x0504, 0x0706, 0x0908, 0x0B0A, 0x0D0C, 0x0F0E,
    0x1110, 0x1312, 0x1514, 0x1716,
    0x2120, 0x2322, 0x3024, 0x3231, 0x4033, 0x4241,
    0x5150, 0x6160, 0x7170,
    0x9080, 0xB0A0, 0xD0C0, 0xF0E0,
    0xFFFF, 0xFFFF, 0xFFFF, 0xFFFF, 0xFFFF, 0xFFFF, 0xFFFF
};

__device__ __forceinline__ float sel16(const float a[16], int i) {
    float b0 = (i & 1) ? a[1] : a[0];
    float b1 = (i & 1) ? a[3] : a[2];
    float b2 = (i & 1) ? a[5] : a[4];
    float b3 = (i & 1) ? a[7] : a[6];
    float b4 = (i & 1) ? a[9] : a[8];
    float b5 = (i & 1) ? a[11] : a[10];
    float b6 = (i & 1) ? a[13] : a[12];
    float b7 = (i & 1) ? a[15] : a[14];
    float c0 = (i & 2) ? b1 : b0;
    float c1 = (i & 2) ? b3 : b2;
    float c2 = (i & 2) ? b5 : b4;
    float c3 = (i & 2) ? b7 : b6;
    float d0 = (i & 4) ? c1 : c0;
    float d1 = (i & 4) ? c3 : c2;
    return (i & 8) ? d1 : d0;
}

__global__ __launch_bounds__(256) void kC_combine(const float* __restrict__ T,
                                                  const float* __restrict__ D,
                                                  unsigned short* __restrict__ Wh,
                                                  unsigned short* __restrict__ Wl) {
    __shared__ unsigned long long ckey[8][50];
    __shared__ float winval[8][16];
    __shared__ int winflat[8][16];
    __shared__ int Wrow[256];

    const int tid = threadIdx.x;
    const int n = blockIdx.x;
    const int h = tid >> 5;
    const int lam = tid & 15;

    Wrow[tid] = 0;

    float sxd[16], syd[16];
    const float* t0 = &T[((size_t)n * 16 + h) * 16];
    const float* t1 = &T[((size_t)n * 16 + 8 + h) * 16];
    #pragma unroll
    for (int q = 0; q < 16; ++q) { sxd[q] = t0[q]; syd[q] = t1[q]; }

    const int lc = tid & 31;
    const unsigned int cw = CAND_TBL[lc];
    unsigned long long mykey[2]; float myval[2]; int myflat[2]; int myrank[2] = {0, 0};
    #pragma unroll
    for (int u = 0; u < 2; ++u) {
        const int fl = (cw >> (8 * u)) & 0xFF;
        const float sv = sel16(sxd, fl >> 4) + sel16(syd, fl & 15);
        const unsigned int uv = __float_as_uint(sv);
        const unsigned int mo = (uv & 0x80000000u) ? ~uv : (uv | 0x80000000u);
        mykey[u] = ((unsigned long long)mo << 8) | (unsigned long long)(255 - fl);
        myval[u] = sv; myflat[u] = fl;
        const int slot = lc * 2 + u;
        if (slot < 50) ckey[h][slot] = mykey[u];
    }
    __syncthreads();
    for (int kk = 0; kk < 50; ++kk) {
        const unsigned long long ok = ckey[h][kk];
        myrank[0] += (ok > mykey[0]) ? 1 : 0;
        myrank[1] += (ok > mykey[1]) ? 1 : 0;
    }
    #pragma unroll
    for (int u = 0; u < 2; ++u)
        if (myrank[u] < 16) { winval[h][myrank[u]] = myval[u]; winflat[h][myrank[u]] = myflat[u]; }
    __syncthreads();

    if (!(tid & 16)) {
        const float sc = winval[h][lam];
        const float m0 = winval[h][0];
        float e = expf(sc - m0);
        float esum = e;
        #pragma unroll
        for (int off = 1; off < 16; off <<= 1) esum += __shfl_xor(esum, off);
        const int fl = winflat[h][lam];
        const float hv = D[(size_t)n * 256 + fl];
        const float gg = 0.5f * hv * (1.0f + erff(hv * 0.70710678118654752f));
        const float wv = (e / esum) * gg;
        atomicAdd(&Wrow[fl], __float2int_rn(wv * 4194304.0f));
    }
    __syncthreads();
    const float wfin = (float)Wrow[tid] * (1.0f / 4194304.0f);
    const unsigned short hh = f32_to_f16(wfin);
    Wh[(size_t)n * 256 + tid] = hh;
    Wl[(size_t)n * 256 + tid] = f32_to_f16(wfin - f16_to_f32(hh));
}

// ---------------- k5: out = W @ up256 via fp16 3-term MFMA. grid (64, 4).
__global__ __launch_bounds__(256) void k5_mfma(const unsigned short* __restrict__ Wh,
                                               const unsigned short* __restrict__ Wl,
                                               const unsigned short* __restrict__ upTh,
                                               const unsigned short* __restrict__ upTl,
                                               float* __restrict__ out) {
    __shared__ __align__(16) char lds[20480];   // A 4KB + B 16KB
    const int tid = threadIdx.x;
    const int w = tid >> 6, l = tid & 63;
    const int n0 = blockIdx.x * 32;
    const int d0 = blockIdx.y * 128;
    f32x4 acc[2][2] = {};

    for (int s = 0; s < 8; ++s) {
        const int kk = s * 32;
        __syncthreads();
        {   // A: W rows 32 x 128B = 4KB
            const int q = w * 1024 + l * 16;
            const int r = q >> 7;
            const int bsw = (q & 127) ^ ((r & 7) << 4);
            const unsigned short* src = (bsw < 64)
                ? Wh + (size_t)(n0 + r) * 256 + kk + (bsw >> 1)
                : Wl + (size_t)(n0 + r) * 256 + kk + ((bsw - 64) >> 1);
            gl_lds16(src, lds + w * 1024);
        }
        #pragma unroll
        for (int t = 0; t < 4; ++t) {   // B: upT rows 128 x 128B = 16KB
            const int q = w * 4096 + t * 1024 + l * 16;
            const int r = q >> 7;
            const int bsw = (q & 127) ^ ((r & 7) << 4);
            const unsigned short* src = (bsw < 64)
                ? upTh + (size_t)(d0 + r) * 256 + kk + (bsw >> 1)
                : upTl + (size_t)(d0 + r) * 256 + kk + ((bsw - 64) >> 1);
            gl_lds16(src, lds + 4096 + w * 4096 + t * 1024);
        }
        __syncthreads();
        const int bq = (l >> 4) * 16;
        f16x8 ah[2], al[2];
        #pragma unroll
        for (int mi = 0; mi < 2; ++mi) {
            const int ra = mi * 16 + (l & 15);
            const int swz = (ra & 7) << 4;
            ah[mi] = *(const f16x8*)(lds + ra * 128 + (bq ^ swz));
            al[mi] = *(const f16x8*)(lds + ra * 128 + ((bq + 64) ^ swz));
        }
        #pragma unroll
        for (int nj = 0; nj < 2; ++nj) {
            const int rb = w * 32 + nj * 16 + (l & 15);
            const int swz = (rb & 7) << 4;
            f16x8 bh = *(const f16x8*)(lds + 4096 + rb * 128 + (bq ^ swz));
            f16x8 bl = *(const f16x8*)(lds + 4096 + rb * 128 + ((bq + 64) ^ swz));
            #pragma unroll
            for (int mi = 0; mi < 2; ++mi) {
                acc[mi][nj] = __builtin_amdgcn_mfma_f32_16x16x32_f16(ah[mi], bh, acc[mi][nj], 0, 0, 0);
                acc[mi][nj] = __builtin_amdgcn_mfma_f32_16x16x32_f16(ah[mi], bl, acc[mi][nj], 0, 0, 0);
                acc[mi][nj] = __builtin_amdgcn_mfma_f32_16x16x32_f16(al[mi], bh, acc[mi][nj], 0, 0, 0);
            }
        }
    }
    #pragma unroll
    for (int mi = 0; mi < 2; ++mi)
        #pragma unroll
        for (int nj = 0; nj < 2; ++nj)
            #pragma unroll
            for (int r = 0; r < 4; ++r) {
                const int row = n0 + mi * 16 + (l >> 4) * 4 + r;
                const int col = d0 + w * 32 + nj * 16 + (l & 15);
                out[(size_t)row * NDIM + col] = acc[mi][nj][r];
            }
}

extern "C" void kernel_launch(void* const* d_in, const int* in_sizes, int n_in,
                              void* d_out, int out_size, void* d_ws, size_t ws_size,
                              hipStream_t stream) {
    const float* x    = (const float*)d_in[0];
    const float* Wq   = (const float*)d_in[1];
    const float* keys = (const float*)d_in[2];
    const float* down = (const float*)d_in[3];
    const float* up   = (const float*)d_in[4];
    float* out = (float*)d_out;

    char* ws = (char*)d_ws;
    unsigned short* Mth  = (unsigned short*)(ws);                  // 4,456,448 B
    unsigned short* Mtl  = (unsigned short*)(ws + 4456448);        // 4,456,448 B
    unsigned short* xh   = (unsigned short*)(ws + 8912896);        // 2,097,152 B
    unsigned short* xl   = (unsigned short*)(ws + 11010048);       // 2,097,152 B
    unsigned short* Wqh  = (unsigned short*)(ws + 13107200);       // 4,194,304 B
    unsigned short* Wql  = (unsigned short*)(ws + 17301504);       // 4,194,304 B
    unsigned short* ksh  = (unsigned short*)(ws + 21495808);       // 2,097,152 B (1,048,576 elems!)
    unsigned short* ksl  = (unsigned short*)(ws + 23592960);       // 2,097,152 B
    unsigned short* upTh = (unsigned short*)(ws + 25690112);       //   262,144 B
    unsigned short* upTl = (unsigned short*)(ws + 25952256);       //   262,144 B
    float* T             = (float*)(ws + 26214400);                // 2,097,152 B
    float* D             = (float*)(ws + 28311552);                // 2,097,152 B
    unsigned short* Wh   = (unsigned short*)(ws + 30408704);       // 1,048,576 B
    unsigned short* Wl   = (unsigned short*)(ws + 31457280);       // 1,048,576 B

    kP_split<<<1344, 256, 0, stream>>>(x, Wq, keys, down, up,
                                       xh, xl, Wqh, Wql, ksh, ksl, Mth, Mtl, upTh, upTl);
    kQ_m1<<<dim3(16, 16), 256, 0, stream>>>(Wqh, Wql, ksh, ksl, Mth, Mtl);
    kF_gemm<<<dim3(32, 17), 256, 0, stream>>>(xh, xl, Mth, Mtl, T, D);
    kC_combine<<<2048, 256, 0, stream>>>(T, D, Wh, Wl);
    k5_mfma<<<dim3(64, 4), 256, 0, stream>>>(Wh, Wl, upTh, upTl, out);
}

// Round 12
// 91.512 us; speedup vs baseline: 1.1974x; 1.0293x over previous
//
#include <hip/hip_runtime.h>
#include <math.h>

#define N_TOK 2048
#define NDIM 512
#define HEADS 8
#define TOPK 16
#define QCOLS 4096

typedef __attribute__((ext_vector_type(8))) _Float16 f16x8;
typedef __attribute__((ext_vector_type(4))) float f32x4;

__device__ __forceinline__ unsigned short f32_to_f16(float f) {
    _Float16 h = (_Float16)f;
    return __builtin_bit_cast(unsigned short, h);
}
__device__ __forceinline__ float f16_to_f32(unsigned short u) {
    return (float)__builtin_bit_cast(_Float16, u);
}
__device__ __forceinline__ void gl_lds16(const void* g, void* l) {
    __builtin_amdgcn_global_load_lds(
        (const __attribute__((address_space(1))) void*)g,
        (__attribute__((address_space(3))) void*)l, 16, 0, 0);
}

// ---------------- kP: all fp32 -> fp16 hi/lo splits (x, Wq, keys, down->Mt rows, upT)
__device__ __forceinline__ void split_f4(const float* __restrict__ src,
                                         unsigned short* __restrict__ dh,
                                         unsigned short* __restrict__ dl,
                                         int i) {
    float4 v = reinterpret_cast<const float4*>(src)[i];
    float vv[4] = {v.x, v.y, v.z, v.w};
    ushort4 h, lo;
    unsigned short* hp = &h.x; unsigned short* lp = &lo.x;
    #pragma unroll
    for (int q = 0; q < 4; ++q) {
        unsigned short hh = f32_to_f16(vv[q]);
        hp[q] = hh;
        lp[q] = f32_to_f16(vv[q] - f16_to_f32(hh));
    }
    reinterpret_cast<ushort4*>(dh)[i] = h;
    reinterpret_cast<ushort4*>(dl)[i] = lo;
}

__global__ __launch_bounds__(256) void kP_split(const float* __restrict__ x,
                                                const float* __restrict__ Wq,
                                                const float* __restrict__ keys,
                                                const float* __restrict__ down,
                                                const float* __restrict__ up,
                                                unsigned short* __restrict__ xh,
                                                unsigned short* __restrict__ xl,
                                                unsigned short* __restrict__ Wqh,
                                                unsigned short* __restrict__ Wql,
                                                unsigned short* __restrict__ ksh,
                                                unsigned short* __restrict__ ksl,
                                                unsigned short* __restrict__ Mth,
                                                unsigned short* __restrict__ Mtl,
                                                unsigned short* __restrict__ upTh,
                                                unsigned short* __restrict__ upTl) {
    const int bid = blockIdx.x;
    const int tid = threadIdx.x;
    if (bid < 256) {                     // x: 262,144 f4 -> 256 blocks
        #pragma unroll
        for (int t = 0; t < 4; ++t) split_f4(x, xh, xl, bid * 1024 + t * 256 + tid);
        return;
    }
    if (bid < 768) {                     // Wq: 524,288 f4 -> 512 blocks
        const int b = bid - 256;
        #pragma unroll
        for (int t = 0; t < 4; ++t) split_f4(Wq, Wqh, Wql, b * 1024 + t * 256 + tid);
        return;
    }
    if (bid < 1024) {                    // keys: 262,144 f4 -> 256 blocks
        const int b = bid - 768;
        #pragma unroll
        for (int t = 0; t < 4; ++t) split_f4(keys, ksh, ksl, b * 1024 + t * 256 + tid);
        return;
    }
    if (bid < 1280) {                    // down row e -> Mt row 4096+e
        const int e = bid - 1024;
        const int d0 = tid * 2;
        float2 v = *reinterpret_cast<const float2*>(&down[(size_t)e * NDIM + d0]);
        ushort2 h, lo;
        unsigned short h0 = f32_to_f16(v.x);
        unsigned short h1 = f32_to_f16(v.y);
        h.x = h0; h.y = h1;
        lo.x = f32_to_f16(v.x - f16_to_f32(h0));
        lo.y = f32_to_f16(v.y - f16_to_f32(h1));
        *reinterpret_cast<ushort2*>(&Mth[(size_t)(QCOLS + e) * NDIM + d0]) = h;
        *reinterpret_cast<ushort2*>(&Mtl[(size_t)(QCOLS + e) * NDIM + d0]) = lo;
        return;
    }
    // upT: up[e][d] -> upTh/upTl[d][e]   (64 blocks)
    const int b = bid - 1280;            // 0..63
    #pragma unroll
    for (int dd = 0; dd < 8; ++dd) {
        const int d = b * 8 + dd;
        const int e = tid;
        const float v = up[(size_t)e * NDIM + d];
        unsigned short hh = f32_to_f16(v);
        upTh[(size_t)d * 256 + e] = hh;
        upTl[(size_t)d * 256 + e] = f32_to_f16(v - f16_to_f32(hh));
    }
}

// ---------------- kQ: M_block = Wq_slice @ keys^T via fp16 3-term MFMA,
// output transposed fp16 hi/lo into Mth/Mtl[col][c]. grid (16 c-tiles, 16 ph).
__global__ __launch_bounds__(256) void kQ_m1(const unsigned short* __restrict__ Wqh,
                                             const unsigned short* __restrict__ Wql,
                                             const unsigned short* __restrict__ ksh,
                                             const unsigned short* __restrict__ ksl,
                                             unsigned short* __restrict__ Mth,
                                             unsigned short* __restrict__ Mtl) {
    __shared__ __align__(16) char lds[36864];   // A 4KB + B 32KB
    const int tid = threadIdx.x;
    const int w = tid >> 6, l = tid & 63;
    const int c0 = blockIdx.x * 32;
    const int ph = blockIdx.y;
    const int p = ph >> 3, h = ph & 7;
    const int off = p * 2048 + h * 256;
    f32x4 acc[2][4] = {};

    for (int s = 0; s < 8; ++s) {
        const int kk = s * 32;
        __syncthreads();
        {   // A: 32 rows x 128B = 4KB
            const int q = w * 1024 + l * 16;
            const int r = q >> 7;
            const int bsw = (q & 127) ^ ((r & 7) << 4);
            const unsigned short* src = (bsw < 64)
                ? Wqh + (size_t)(c0 + r) * QCOLS + off + kk + (bsw >> 1)
                : Wql + (size_t)(c0 + r) * QCOLS + off + kk + ((bsw - 64) >> 1);
            gl_lds16(src, lds + w * 1024);
        }
        #pragma unroll
        for (int t = 0; t < 8; ++t) {   // B: 256 rows x 128B = 32KB
            const int q = w * 8192 + t * 1024 + l * 16;
            const int r = q >> 7;
            const int bsw = (q & 127) ^ ((r & 7) << 4);
            const unsigned short* src = (bsw < 64)
                ? ksh + ((size_t)(h * 256 + r) * 2 + p) * 256 + kk + (bsw >> 1)
                : ksl + ((size_t)(h * 256 + r) * 2 + p) * 256 + kk + ((bsw - 64) >> 1);
            gl_lds16(src, lds + 4096 + w * 8192 + t * 1024);
        }
        __syncthreads();
        const int bq = (l >> 4) * 16;
        f16x8 ah[2], al[2];
        #pragma unroll
        for (int mi = 0; mi < 2; ++mi) {
            const int ra = mi * 16 + (l & 15);
            const int swz = (ra & 7) << 4;
            ah[mi] = *(const f16x8*)(lds + ra * 128 + (bq ^ swz));
            al[mi] = *(const f16x8*)(lds + ra * 128 + ((bq + 64) ^ swz));
        }
        __builtin_amdgcn_s_setprio(1);
        #pragma unroll
        for (int nj = 0; nj < 4; ++nj) {
            const int rb = w * 64 + nj * 16 + (l & 15);
            const int swz = (rb & 7) << 4;
            f16x8 bh = *(const f16x8*)(lds + 4096 + rb * 128 + (bq ^ swz));
            f16x8 bl = *(const f16x8*)(lds + 4096 + rb * 128 + ((bq + 64) ^ swz));
            #pragma unroll
            for (int mi = 0; mi < 2; ++mi) {
                acc[mi][nj] = __builtin_amdgcn_mfma_f32_16x16x32_f16(ah[mi], bh, acc[mi][nj], 0, 0, 0);
                acc[mi][nj] = __builtin_amdgcn_mfma_f32_16x16x32_f16(ah[mi], bl, acc[mi][nj], 0, 0, 0);
                acc[mi][nj] = __builtin_amdgcn_mfma_f32_16x16x32_f16(al[mi], bh, acc[mi][nj], 0, 0, 0);
            }
        }
        __builtin_amdgcn_s_setprio(0);
    }
    #pragma unroll
    for (int mi = 0; mi < 2; ++mi)
        #pragma unroll
        for (int nj = 0; nj < 4; ++nj) {
            const int k = w * 64 + nj * 16 + (l & 15);
            const int cb = c0 + mi * 16 + (l >> 4) * 4;
            ushort4 h4, l4;
            unsigned short* hp = &h4.x; unsigned short* lp = &l4.x;
            #pragma unroll
            for (int r = 0; r < 4; ++r) {
                const float v = acc[mi][nj][r];
                unsigned short hh = f32_to_f16(v);
                hp[r] = hh;
                lp[r] = f32_to_f16(v - f16_to_f32(hh));
            }
            *reinterpret_cast<ushort4*>(&Mth[(size_t)(off + k) * NDIM + cb]) = h4;
            *reinterpret_cast<ushort4*>(&Mtl[(size_t)(off + k) * NDIM + cb]) = l4;
        }
}

// ---------------- KF: fused sim GEMM + phase-1 half-group top-16.
// BM=128, BN=128, BK=32, double-buffered (stage next before compute), grid (16,34).
// by<32: score half-group (colbase = by*128) -> sorted top-16 of 128 -> T[n][by][16].
// by>=32: D half (colbase = by*128 = 4096/4224) -> D[2048][256] direct store.
#define BM 128
#define BN 128
#define BK 32
#define KFBUF 32768
__global__ __launch_bounds__(256, 2) void kF_gemm(const unsigned short* __restrict__ xh,
                                                  const unsigned short* __restrict__ xl,
                                                  const unsigned short* __restrict__ Mth,
                                                  const unsigned short* __restrict__ Mtl,
                                                  float* __restrict__ T,
                                                  float* __restrict__ D) {
    __shared__ __align__(16) char lds[2 * KFBUF];   // 64 KB
    const int tid = threadIdx.x;
    const int w = tid >> 6, l = tid & 63;
    const int row0 = blockIdx.x * BM;
    const int by = blockIdx.y;
    const int colbase = by * 128;      // score groups AND D rows (4096/4224) both
    f32x4 acc[8][2] = {};

    auto stage = [&](int buf, int s) {
        const int kk = s * BK;
        char* base = lds + buf * KFBUF;
        #pragma unroll
        for (int t = 0; t < 4; ++t) {                 // A: 128 rows x 128B = 16KB
            const int q = w * 4096 + t * 1024 + l * 16;
            const int r = q >> 7;
            const int bsw = (q & 127) ^ ((r & 7) << 4);
            const unsigned short* src = (bsw < 64)
                ? xh + (size_t)(row0 + r) * NDIM + kk + (bsw >> 1)
                : xl + (size_t)(row0 + r) * NDIM + kk + ((bsw - 64) >> 1);
            gl_lds16(src, base + w * 4096 + t * 1024);
        }
        #pragma unroll
        for (int t = 0; t < 4; ++t) {                 // B: 128 rows x 128B = 16KB
            const int q = w * 4096 + t * 1024 + l * 16;
            const int r = q >> 7;
            const int bsw = (q & 127) ^ ((r & 7) << 4);
            const unsigned short* src = (bsw < 64)
                ? Mth + (size_t)(colbase + r) * NDIM + kk + (bsw >> 1)
                : Mtl + (size_t)(colbase + r) * NDIM + kk + ((bsw - 64) >> 1);
            gl_lds16(src, base + 16384 + w * 4096 + t * 1024);
        }
    };

    stage(0, 0);
    __syncthreads();
    for (int s = 0; s < 16; ++s) {
        if (s + 1 < 16) stage((s + 1) & 1, s + 1);
        const char* base = lds + (s & 1) * KFBUF;
        const int bq = (l >> 4) * 16;
        f16x8 bh[2], bl[2];
        #pragma unroll
        for (int nj = 0; nj < 2; ++nj) {
            const int rb = w * 32 + nj * 16 + (l & 15);
            const int swz = (rb & 7) << 4;
            bh[nj] = *(const f16x8*)(base + 16384 + rb * 128 + (bq ^ swz));
            bl[nj] = *(const f16x8*)(base + 16384 + rb * 128 + ((bq + 64) ^ swz));
        }
        __builtin_amdgcn_s_setprio(1);
        #pragma unroll
        for (int mi = 0; mi < 8; ++mi) {
            const int ra = mi * 16 + (l & 15);
            const int swz = (ra & 7) << 4;
            f16x8 ah = *(const f16x8*)(base + ra * 128 + (bq ^ swz));
            f16x8 al = *(const f16x8*)(base + ra * 128 + ((bq + 64) ^ swz));
            #pragma unroll
            for (int nj = 0; nj < 2; ++nj) {
                acc[mi][nj] = __builtin_amdgcn_mfma_f32_16x16x32_f16(ah, bh[nj], acc[mi][nj], 0, 0, 0);
                acc[mi][nj] = __builtin_amdgcn_mfma_f32_16x16x32_f16(ah, bl[nj], acc[mi][nj], 0, 0, 0);
                acc[mi][nj] = __builtin_amdgcn_mfma_f32_16x16x32_f16(al, bh[nj], acc[mi][nj], 0, 0, 0);
            }
        }
        __builtin_amdgcn_s_setprio(0);
        __syncthreads();   // drains vmcnt (next stage) + protects buffer reuse
    }

    if (by >= 32) {     // D half-block: direct store
        #pragma unroll
        for (int mi = 0; mi < 8; ++mi)
            #pragma unroll
            for (int nj = 0; nj < 2; ++nj)
                #pragma unroll
                for (int r = 0; r < 4; ++r) {
                    const int row = row0 + mi * 16 + (l >> 4) * 4 + r;
                    const int col = (by - 32) * 128 + w * 32 + nj * 16 + (l & 15);
                    D[(size_t)row * 256 + col] = acc[mi][nj][r];
                }
        return;
    }

    // epilogue: 4 chunks of 32 rows; Cl[32][136] = 17.4KB (fits buf0 region).
    // 8-lane groups: 32 groups x 1 row per chunk, 16 values/lane.
    float* Cl = (float*)lds;
    const int grp8 = tid >> 3;          // 0..31
    const int lam8 = tid & 7;
    for (int c = 0; c < 4; ++c) {
        #pragma unroll
        for (int mm = 0; mm < 2; ++mm) {
            const int mi = c * 2 + mm;
            #pragma unroll
            for (int nj = 0; nj < 2; ++nj)
                #pragma unroll
                for (int r = 0; r < 4; ++r)
                    Cl[(mm * 16 + (l >> 4) * 4 + r) * 136 + w * 32 + nj * 16 + (l & 15)] = acc[mi][nj][r];
        }
        __syncthreads();
        float v[16];
        #pragma unroll
        for (int j = 0; j < 16; ++j) v[j] = Cl[grp8 * 136 + lam8 + 8 * j];
        // in-lane bitonic sort ascending (16 values)
        #pragma unroll
        for (int k = 2; k <= 16; k <<= 1)
            #pragma unroll
            for (int j = k >> 1; j > 0; j >>= 1)
                #pragma unroll
                for (int i = 0; i < 16; ++i) {
                    const int l2 = i ^ j;
                    if (l2 > i) {
                        const bool asc = ((i & k) == 0);
                        const float lo = fminf(v[i], v[l2]), hi = fmaxf(v[i], v[l2]);
                        v[i] = asc ? lo : hi;
                        v[l2] = asc ? hi : lo;
                    }
                }
        // 3 cross-lane merge levels within 8-lane group: keep top-16 multiset
        #pragma unroll
        for (int lvl = 1; lvl <= 4; lvl <<= 1) {
            float m[16];
            #pragma unroll
            for (int q = 0; q < 16; ++q)
                m[q] = fmaxf(v[q], __shfl_xor(v[15 - q], lvl));
            #pragma unroll
            for (int j = 8; j > 0; j >>= 1)
                #pragma unroll
                for (int i = 0; i < 16; ++i) {
                    const int l2 = i ^ j;
                    if (l2 > i) {
                        const float lo = fminf(m[i], m[l2]), hi = fmaxf(m[i], m[l2]);
                        m[i] = lo; m[l2] = hi;
                    }
                }
            #pragma unroll
            for (int q = 0; q < 16; ++q) v[q] = m[q];
        }
        // lane lam8 writes ranks 2*lam8 and 2*lam8+1 (descending)
        const int n = row0 + c * 32 + grp8;
        T[((size_t)n * 32 + by) * 16 + 2 * lam8]     = v[15 - 2 * lam8];
        T[((size_t)n * 32 + by) * 16 + 2 * lam8 + 1] = v[14 - 2 * lam8];
        __syncthreads();
    }
}

// ---------------- KC: merge half-lists -> 50 monotone candidates -> top-16 ->
// softmax*gelu(D) -> dense W as fp16 hi/lo
__device__ const unsigned short CAND_TBL[32] = {
    0x0100, 0x0302, 0x0504, 0x0706, 0x0908, 0x0B0A, 0x0D0C, 0x0F0E,
    0x1110, 0x1312, 0x1514, 0x1716,
    0x2120, 0x2322, 0x3024, 0x3231, 0x4033, 0x4241,
    0x5150, 0x6160, 0x7170,
    0x9080, 0xB0A0, 0xD0C0, 0xF0E0,
    0xFFFF, 0xFFFF, 0xFFFF, 0xFFFF, 0xFFFF, 0xFFFF, 0xFFFF
};

__device__ __forceinline__ float sel16(const float a[16], int i) {
    float b0 = (i & 1) ? a[1] : a[0];
    float b1 = (i & 1) ? a[3] : a[2];
    float b2 = (i & 1) ? a[5] : a[4];
    float b3 = (i & 1) ? a[7] : a[6];
    float b4 = (i & 1) ? a[9] : a[8];
    float b5 = (i & 1) ? a[11] : a[10];
    float b6 = (i & 1) ? a[13] : a[12];
    float b7 = (i & 1) ? a[15] : a[14];
    float c0 = (i & 2) ? b1 : b0;
    float c1 = (i & 2) ? b3 : b2;
    float c2 = (i & 2) ? b5 : b4;
    float c3 = (i & 2) ? b7 : b6;
    float d0 = (i & 4) ? c1 : c0;
    float d1 = (i & 4) ? c3 : c2;
    return (i & 8) ? d1 : d0;
}

// merge two descending 16-lists -> descending top-16 of the union (bitonic lemma)
__device__ __forceinline__ void merge_desc16(const float* __restrict__ a,
                                             const float* __restrict__ b,
                                             float out_desc[16]) {
    float m[16];
    #pragma unroll
    for (int q = 0; q < 16; ++q) m[q] = fmaxf(a[q], b[15 - q]);
    // m holds the top-16 multiset (bitonic order) -> full in-lane ascending sort
    #pragma unroll
    for (int k = 2; k <= 16; k <<= 1)
        #pragma unroll
        for (int j = k >> 1; j > 0; j >>= 1)
            #pragma unroll
            for (int i = 0; i < 16; ++i) {
                const int l2 = i ^ j;
                if (l2 > i) {
                    const bool asc = ((i & k) == 0);
                    const float lo = fminf(m[i], m[l2]), hi = fmaxf(m[i], m[l2]);
                    m[i] = asc ? lo : hi;
                    m[l2] = asc ? hi : lo;
                }
            }
    #pragma unroll
    for (int q = 0; q < 16; ++q) out_desc[q] = m[15 - q];
}

__global__ __launch_bounds__(256) void kC_combine(const float* __restrict__ T,
                                                  const float* __restrict__ D,
                                                  unsigned short* __restrict__ Wh,
                                                  unsigned short* __restrict__ Wl) {
    __shared__ unsigned long long ckey[8][50];
    __shared__ float winval[8][16];
    __shared__ int winflat[8][16];
    __shared__ int Wrow[256];

    const int tid = threadIdx.x;
    const int n = blockIdx.x;
    const int h = tid >> 5;
    const int lam = tid & 15;

    Wrow[tid] = 0;

    float a0[16], a1[16], b0v[16], b1v[16];
    const float* t00 = &T[((size_t)n * 32 + 2 * h) * 16];       // p0 half0
    const float* t01 = &T[((size_t)n * 32 + 2 * h + 1) * 16];   // p0 half1
    const float* t10 = &T[((size_t)n * 32 + 16 + 2 * h) * 16];  // p1 half0
    const float* t11 = &T[((size_t)n * 32 + 17 + 2 * h) * 16];  // p1 half1
    #pragma unroll
    for (int q = 0; q < 16; ++q) {
        a0[q] = t00[q]; a1[q] = t01[q];
        b0v[q] = t10[q]; b1v[q] = t11[q];
    }
    float sxd[16], syd[16];
    merge_desc16(a0, a1, sxd);
    merge_desc16(b0v, b1v, syd);

    const int lc = tid & 31;
    const unsigned int cw = CAND_TBL[lc];
    unsigned long long mykey[2]; float myval[2]; int myflat[2]; int myrank[2] = {0, 0};
    #pragma unroll
    for (int u = 0; u < 2; ++u) {
        const int fl = (cw >> (8 * u)) & 0xFF;
        const float sv = sel16(sxd, fl >> 4) + sel16(syd, fl & 15);
        const unsigned int uv = __float_as_uint(sv);
        const unsigned int mo = (uv & 0x80000000u) ? ~uv : (uv | 0x80000000u);
        mykey[u] = ((unsigned long long)mo << 8) | (unsigned long long)(255 - fl);
        myval[u] = sv; myflat[u] = fl;
        const int slot = lc * 2 + u;
        if (slot < 50) ckey[h][slot] = mykey[u];
    }
    __syncthreads();
    for (int kk = 0; kk < 50; ++kk) {
        const unsigned long long ok = ckey[h][kk];
        myrank[0] += (ok > mykey[0]) ? 1 : 0;
        myrank[1] += (ok > mykey[1]) ? 1 : 0;
    }
    #pragma unroll
    for (int u = 0; u < 2; ++u)
        if (myrank[u] < 16) { winval[h][myrank[u]] = myval[u]; winflat[h][myrank[u]] = myflat[u]; }
    __syncthreads();

    if (!(tid & 16)) {
        const float sc = winval[h][lam];
        const float m0 = winval[h][0];
        float e = expf(sc - m0);
        float esum = e;
        #pragma unroll
        for (int off = 1; off < 16; off <<= 1) esum += __shfl_xor(esum, off);
        const int fl = winflat[h][lam];
        const float hv = D[(size_t)n * 256 + fl];
        const float gg = 0.5f * hv * (1.0f + erff(hv * 0.70710678118654752f));
        const float wv = (e / esum) * gg;
        atomicAdd(&Wrow[fl], __float2int_rn(wv * 4194304.0f));
    }
    __syncthreads();
    const float wfin = (float)Wrow[tid] * (1.0f / 4194304.0f);
    const unsigned short hh = f32_to_f16(wfin);
    Wh[(size_t)n * 256 + tid] = hh;
    Wl[(size_t)n * 256 + tid] = f32_to_f16(wfin - f16_to_f32(hh));
}

// ---------------- k5: out = W @ up256 via fp16 3-term MFMA. grid (64, 4).
__global__ __launch_bounds__(256) void k5_mfma(const unsigned short* __restrict__ Wh,
                                               const unsigned short* __restrict__ Wl,
                                               const unsigned short* __restrict__ upTh,
                                               const unsigned short* __restrict__ upTl,
                                               float* __restrict__ out) {
    __shared__ __align__(16) char lds[20480];   // A 4KB + B 16KB
    const int tid = threadIdx.x;
    const int w = tid >> 6, l = tid & 63;
    const int n0 = blockIdx.x * 32;
    const int d0 = blockIdx.y * 128;
    f32x4 acc[2][2] = {};

    for (int s = 0; s < 8; ++s) {
        const int kk = s * 32;
        __syncthreads();
        {   // A: W rows 32 x 128B = 4KB
            const int q = w * 1024 + l * 16;
            const int r = q >> 7;
            const int bsw = (q & 127) ^ ((r & 7) << 4);
            const unsigned short* src = (bsw < 64)
                ? Wh + (size_t)(n0 + r) * 256 + kk + (bsw >> 1)
                : Wl + (size_t)(n0 + r) * 256 + kk + ((bsw - 64) >> 1);
            gl_lds16(src, lds + w * 1024);
        }
        #pragma unroll
        for (int t = 0; t < 4; ++t) {   // B: upT rows 128 x 128B = 16KB
            const int q = w * 4096 + t * 1024 + l * 16;
            const int r = q >> 7;
            const int bsw = (q & 127) ^ ((r & 7) << 4);
            const unsigned short* src = (bsw < 64)
                ? upTh + (size_t)(d0 + r) * 256 + kk + (bsw >> 1)
                : upTl + (size_t)(d0 + r) * 256 + kk + ((bsw - 64) >> 1);
            gl_lds16(src, lds + 4096 + w * 4096 + t * 1024);
        }
        __syncthreads();
        const int bq = (l >> 4) * 16;
        f16x8 ah[2], al[2];
        #pragma unroll
        for (int mi = 0; mi < 2; ++mi) {
            const int ra = mi * 16 + (l & 15);
            const int swz = (ra & 7) << 4;
            ah[mi] = *(const f16x8*)(lds + ra * 128 + (bq ^ swz));
            al[mi] = *(const f16x8*)(lds + ra * 128 + ((bq + 64) ^ swz));
        }
        #pragma unroll
        for (int nj = 0; nj < 2; ++nj) {
            const int rb = w * 32 + nj * 16 + (l & 15);
            const int swz = (rb & 7) << 4;
            f16x8 bh = *(const f16x8*)(lds + 4096 + rb * 128 + (bq ^ swz));
            f16x8 bl = *(const f16x8*)(lds + 4096 + rb * 128 + ((bq + 64) ^ swz));
            #pragma unroll
            for (int mi = 0; mi < 2; ++mi) {
                acc[mi][nj] = __builtin_amdgcn_mfma_f32_16x16x32_f16(ah[mi], bh, acc[mi][nj], 0, 0, 0);
                acc[mi][nj] = __builtin_amdgcn_mfma_f32_16x16x32_f16(ah[mi], bl, acc[mi][nj], 0, 0, 0);
                acc[mi][nj] = __builtin_amdgcn_mfma_f32_16x16x32_f16(al[mi], bh, acc[mi][nj], 0, 0, 0);
            }
        }
    }
    #pragma unroll
    for (int mi = 0; mi < 2; ++mi)
        #pragma unroll
        for (int nj = 0; nj < 2; ++nj)
            #pragma unroll
            for (int r = 0; r < 4; ++r) {
                const int row = n0 + mi * 16 + (l >> 4) * 4 + r;
                const int col = d0 + w * 32 + nj * 16 + (l & 15);
                out[(size_t)row * NDIM + col] = acc[mi][nj][r];
            }
}

extern "C" void kernel_launch(void* const* d_in, const int* in_sizes, int n_in,
                              void* d_out, int out_size, void* d_ws, size_t ws_size,
                              hipStream_t stream) {
    const float* x    = (const float*)d_in[0];
    const float* Wq   = (const float*)d_in[1];
    const float* keys = (const float*)d_in[2];
    const float* down = (const float*)d_in[3];
    const float* up   = (const float*)d_in[4];
    float* out = (float*)d_out;

    char* ws = (char*)d_ws;
    unsigned short* Mth  = (unsigned short*)(ws);                  // 4,456,448 B
    unsigned short* Mtl  = (unsigned short*)(ws + 4456448);        // 4,456,448 B
    unsigned short* xh   = (unsigned short*)(ws + 8912896);        // 2,097,152 B
    unsigned short* xl   = (unsigned short*)(ws + 11010048);       // 2,097,152 B
    unsigned short* Wqh  = (unsigned short*)(ws + 13107200);       // 4,194,304 B
    unsigned short* Wql  = (unsigned short*)(ws + 17301504);       // 4,194,304 B
    unsigned short* ksh  = (unsigned short*)(ws + 21495808);       // 2,097,152 B
    unsigned short* ksl  = (unsigned short*)(ws + 23592960);       // 2,097,152 B
    unsigned short* upTh = (unsigned short*)(ws + 25690112);       //   262,144 B
    unsigned short* upTl = (unsigned short*)(ws + 25952256);       //   262,144 B
    float* T             = (float*)(ws + 26214400);                // 4,194,304 B (2048*32*16*4)
    float* D             = (float*)(ws + 30408704);                // 2,097,152 B
    unsigned short* Wh   = (unsigned short*)(ws + 32505856);       // 1,048,576 B
    unsigned short* Wl   = (unsigned short*)(ws + 33554432);       // 1,048,576 B

    kP_split<<<1344, 256, 0, stream>>>(x, Wq, keys, down, up,
                                       xh, xl, Wqh, Wql, ksh, ksl, Mth, Mtl, upTh, upTl);
    kQ_m1<<<dim3(16, 16), 256, 0, stream>>>(Wqh, Wql, ksh, ksl, Mth, Mtl);
    kF_gemm<<<dim3(16, 34), 256, 0, stream>>>(xh, xl, Mth, Mtl, T, D);
    kC_combine<<<2048, 256, 0, stream>>>(T, D, Wh, Wl);
    k5_mfma<<<dim3(64, 4), 256, 0, stream>>>(Wh, Wl, upTh, upTl, out);
}